// Round 4
// baseline (271.090 us; speedup 1.0000x reference)
//
#include <hip/hip_runtime.h>

// HashLoss: contrastive (logsumexp over ln@ln^T/0.2) + 0.5*MSE(H@H^T/128, Tn@Tn^T)
//         + 0.01*mean||logits|-1|
// B=4096. P[4096][1024] bf16 = [ln | hash/sqrt128 | tn]. One mega kernel:
//  - blocks 0..527:    D-role: 128x128 triangle tiles of Hs@Hs^T - T@T^T (K=896)
//  - blocks 528..1055: S-role: 128x128 triangle tiles of ln@ln^T (K=128) + mask epilogue
//  - last finished block inlines the finalize (done-counter, agent-scope atomics)

typedef unsigned short u16x8 __attribute__((ext_vector_type(8)));
typedef __bf16 bf16x8 __attribute__((ext_vector_type(8)));
typedef float f32x4 __attribute__((ext_vector_type(4)));

__device__ __forceinline__ unsigned short f2bf(float f) {
  union { float f; unsigned int u; } v; v.f = f;
  unsigned int u = v.u;
  return (unsigned short)((u + 0x7FFFu + ((u >> 16) & 1u)) >> 16);  // RNE
}

// ---- prep: one wave per row. 1024 blocks x 256 threads.
__global__ __launch_bounds__(256) void prep(const float* __restrict__ logits,
                                            const float* __restrict__ hash,
                                            const float* __restrict__ teacher,
                                            unsigned short* __restrict__ P,
                                            float* __restrict__ qpart,
                                            float* __restrict__ rowexp,
                                            float* __restrict__ possum,
                                            float* __restrict__ cntw,
                                            float* __restrict__ dtot,
                                            int* __restrict__ done) {
  const int r = blockIdx.x * 4 + (threadIdx.x >> 6);
  const int lane = threadIdx.x & 63;
  float tv[12];
  float ss = 0.f;
#pragma unroll
  for (int i = 0; i < 12; ++i) {
    tv[i] = teacher[(size_t)r * 768 + i * 64 + lane];
    ss += tv[i] * tv[i];
  }
  const float l0 = logits[(size_t)r * 128 + lane];
  const float l1 = logits[(size_t)r * 128 + 64 + lane];
  const float h0 = hash[(size_t)r * 128 + lane];
  const float h1 = hash[(size_t)r * 128 + 64 + lane];
  float ssl = l0 * l0 + l1 * l1;
  float qv = fabsf(fabsf(l0) - 1.f) + fabsf(fabsf(l1) - 1.f);
#pragma unroll
  for (int off = 1; off < 64; off <<= 1) {
    ss += __shfl_xor(ss, off, 64);
    ssl += __shfl_xor(ssl, off, 64);
    qv += __shfl_xor(qv, off, 64);
  }
  const float rnt = 1.f / fmaxf(sqrtf(ss), 1e-12f);
  const float rnl = 1.f / fmaxf(sqrtf(ssl), 1e-12f);
  unsigned short* Pr = P + (size_t)r * 1024;
  Pr[lane] = f2bf(l0 * rnl);
  Pr[64 + lane] = f2bf(l1 * rnl);
  // (H/sqrt128)@(H/sqrt128)^T == H@H^T/128
  Pr[128 + lane] = f2bf(h0 * 0.08838834764831845f);
  Pr[192 + lane] = f2bf(h1 * 0.08838834764831845f);
#pragma unroll
  for (int i = 0; i < 12; ++i) Pr[256 + i * 64 + lane] = f2bf(tv[i] * rnt);
  if (lane == 0) {
    qpart[r] = qv;
    rowexp[r] = 0.f; possum[r] = 0.f; cntw[r] = 0.f;
    if (r == 0) { *dtot = 0.f; *done = 0; }
  }
}

// Stage 128 rows x 64 cols of P (A: rows ti+, and if offdiag B: rows tj+) via
// global_load_lds(16B). LDS[row][slot] = global[row][slot ^ (row&7)], pitch 64.
#define STAGE64(COL0)                                                          \
  {                                                                            \
    _Pragma("unroll") for (int it = 0; it < 4; ++it) {                         \
      const int task = it * 256 + t;                                           \
      const int row = task >> 3;                                               \
      const int g = (task & 7) ^ (row & 7);                                    \
      const unsigned short* gpA =                                              \
          P + (size_t)(ti + row) * 1024 + (COL0) + g * 8;                      \
      __builtin_amdgcn_global_load_lds(                                        \
          (const __attribute__((address_space(1))) void*)gpA,                  \
          (__attribute__((address_space(3))) void*)&S[it * 2048 + wave * 512], \
          16, 0, 0);                                                           \
      if (offdiag) {                                                           \
        const unsigned short* gpB =                                            \
            P + (size_t)(tj + row) * 1024 + (COL0) + g * 8;                    \
        __builtin_amdgcn_global_load_lds(                                      \
            (const __attribute__((address_space(1))) void*)gpB,                \
            (__attribute__((address_space(3)))                                 \
                 void*)&S[8192 + it * 2048 + wave * 512],                      \
            16, 0, 0);                                                         \
      }                                                                        \
    }                                                                          \
  }

// 2 k-steps x 16 MFMA on the staged 64-col chunk. Wave (wy,wx) owns the
// 64x64 quadrant at rows wy*64, cols wx*64 as 4x4 tiles of 16x16.
#define MFMA_CHUNK()                                                           \
  {                                                                            \
    _Pragma("unroll") for (int ks = 0; ks < 2; ++ks) {                         \
      bf16x8 af[4], bfr[4];                                                    \
      _Pragma("unroll") for (int rt = 0; rt < 4; ++rt) {                       \
        const int ar = wy * 64 + rt * 16 + l15;                                \
        af[rt] =                                                               \
            *(const bf16x8*)&S[ar * 64 + ((ks * 4 + qd) ^ (l15 & 7)) * 8];     \
      }                                                                        \
      _Pragma("unroll") for (int ct = 0; ct < 4; ++ct) {                       \
        const int br = wx * 64 + ct * 16 + l15;                                \
        bfr[ct] = *(const bf16x8*)&S[boff + br * 64 +                          \
                                     ((ks * 4 + qd) ^ (l15 & 7)) * 8];         \
      }                                                                        \
      _Pragma("unroll") for (int rt = 0; rt < 4; ++rt)                         \
          _Pragma("unroll") for (int ct = 0; ct < 4; ++ct) acc[rt][ct] =       \
          __builtin_amdgcn_mfma_f32_16x16x32_bf16(af[rt], bfr[ct],             \
                                                  acc[rt][ct], 0, 0, 0);       \
    }                                                                          \
  }

__global__ __launch_bounds__(256, 3) void mega(const unsigned short* __restrict__ P,
                                               const void* __restrict__ mask,
                                               float* __restrict__ rowexp,
                                               float* __restrict__ possum,
                                               float* __restrict__ cntw,
                                               float* __restrict__ dtot,
                                               int* __restrict__ done,
                                               const float* __restrict__ qpart,
                                               float* __restrict__ out) {
  __shared__ __align__(16) unsigned short S[16384];  // A @0, B @8192 (shorts)
  __shared__ float redrow[128][2], redcol[128][2], red4[4];
  __shared__ float fc[4], fq[4];
  __shared__ int lastf;

  const int t = threadIdx.x;
  const int wave = t >> 6, lane = t & 63;
  const int qd = lane >> 4, l15 = lane & 15;
  const int wy = wave >> 1, wx = wave & 1;

  const int b = (int)blockIdx.x;
  const bool isD = b < 528;
  const int bb = isD ? b : b - 528;
  // XCD swizzle (528 = 8*66), then triangle decode over 32 block-rows.
  const int l = (bb & 7) * 66 + (bb >> 3);
  int bi = (int)((65.0f - sqrtf(4225.0f - 8.0f * (float)l)) * 0.5f);
  while (bi * (65 - bi) / 2 > l) --bi;
  while ((bi + 1) * (64 - bi) / 2 <= l) ++bi;
  const int bj = bi + (l - bi * (65 - bi) / 2);
  const int ti = bi * 128, tj = bj * 128;
  const bool offdiag = (bi != bj);
  const int boff = offdiag ? 8192 : 0;

  f32x4 acc[4][4];
#pragma unroll
  for (int rt = 0; rt < 4; ++rt)
#pragma unroll
    for (int ct = 0; ct < 4; ++ct) acc[rt][ct] = {0.f, 0.f, 0.f, 0.f};

  if (isD) {
    // D = Hs@Hs^T - T@T^T : chunks 0..11 = T (cols 256..1023), then negate,
    // chunks 12..13 = Hs (cols 128..255).
    for (int kc = 0; kc < 14; ++kc) {
      const int col0 = (kc < 12) ? (256 + kc * 64) : (128 + (kc - 12) * 64);
      __syncthreads();
      STAGE64(col0);
      __syncthreads();
      if (kc == 12) {
#pragma unroll
        for (int rt = 0; rt < 4; ++rt)
#pragma unroll
          for (int ct = 0; ct < 4; ++ct) acc[rt][ct] = -acc[rt][ct];
      }
      MFMA_CHUNK();
    }
    float dsum = 0.f;
#pragma unroll
    for (int rt = 0; rt < 4; ++rt)
#pragma unroll
      for (int ct = 0; ct < 4; ++ct)
#pragma unroll
        for (int i = 0; i < 4; ++i) dsum += acc[rt][ct][i] * acc[rt][ct][i];
#pragma unroll
    for (int off = 1; off < 64; off <<= 1) dsum += __shfl_xor(dsum, off, 64);
    if (lane == 0) red4[wave] = dsum;
    __syncthreads();
    if (t == 0)
      atomicAdd(dtot, (offdiag ? 2.0f : 1.0f) *
                          (red4[0] + red4[1] + red4[2] + red4[3]));
  } else {
    // S-role: ln gram, K=128 (cols 0..127).
    for (int kc = 0; kc < 2; ++kc) {
      const int col0 = kc * 64;
      __syncthreads();
      STAGE64(col0);
      __syncthreads();
      MFMA_CHUNK();
    }

    // ---- mask tiles -> LDS (coalesced), reusing S ----
    __syncthreads();
    unsigned char* MD = (unsigned char*)S;          // [mrow][ncol], 16KB
    unsigned char* MM = (unsigned char*)S + 16384;  // [ncol][mrow], 16KB
    const bool is_byte = ((const unsigned char*)mask)[4097] != 0;
    if (is_byte) {
      const unsigned char* m8 = (const unsigned char*)mask;
#pragma unroll
      for (int it = 0; it < 4; ++it) {
        const int task = it * 256 + t;
        const int row = task >> 3, seg = task & 7;
        *(uint4*)&MD[row * 128 + seg * 16] =
            *(const uint4*)&m8[(size_t)(ti + row) * 4096 + tj + seg * 16];
        if (offdiag)
          *(uint4*)&MM[row * 128 + seg * 16] =
              *(const uint4*)&m8[(size_t)(tj + row) * 4096 + ti + seg * 16];
      }
    } else {
      const unsigned int* m32 = (const unsigned int*)mask;
#pragma unroll
      for (int it = 0; it < 16; ++it) {
        const int task = it * 256 + t;
        const int row = task >> 5, seg = task & 31;
        uint4 v = *(const uint4*)&m32[(size_t)(ti + row) * 4096 + tj + seg * 4];
        uchar4 pk;
        pk.x = v.x ? 1 : 0; pk.y = v.y ? 1 : 0;
        pk.z = v.z ? 1 : 0; pk.w = v.w ? 1 : 0;
        *(uchar4*)&MD[row * 128 + seg * 4] = pk;
        if (offdiag) {
          uint4 w = *(const uint4*)&m32[(size_t)(tj + row) * 4096 + ti + seg * 4];
          uchar4 pm;
          pm.x = w.x ? 1 : 0; pm.y = w.y ? 1 : 0;
          pm.z = w.z ? 1 : 0; pm.w = w.w ? 1 : 0;
          *(uchar4*)&MM[row * 128 + seg * 4] = pm;
        }
      }
    }
    __syncthreads();

    float colp[4] = {0.f, 0.f, 0.f, 0.f};
#pragma unroll
    for (int rt = 0; rt < 4; ++rt) {
#pragma unroll
      for (int r = 0; r < 4; ++r) {
        const int mrow = wy * 64 + rt * 16 + qd * 4 + r;  // C/D: row=qd*4+reg
        const int m = ti + mrow;
        float se = 0.f;
#pragma unroll
        for (int ct = 0; ct < 4; ++ct) {
          const int ncol = wx * 64 + ct * 16 + l15;       // C/D: col=lane&15
          const int n = tj + ncol;
          const float sim = acc[rt][ct][r] * 5.0f;        // /TEMPERATURE
          const float e = __expf(sim);
          if (offdiag || mrow != ncol) se += e;           // diag excluded
          if (offdiag) colp[ct] += e;
          if (MD[mrow * 128 + ncol]) {                    // sparse positives
            atomicAdd(&possum[m], sim);
            atomicAdd(&cntw[m], 1.0f);
          }
          if (offdiag && MM[ncol * 128 + mrow]) {         // mirror (n, m)
            atomicAdd(&possum[n], sim);
            atomicAdd(&cntw[n], 1.0f);
          }
        }
#pragma unroll
        for (int off = 1; off < 16; off <<= 1) se += __shfl_xor(se, off, 64);
        if (l15 == 0) redrow[mrow][wx] = se;
      }
    }
    if (offdiag) {
#pragma unroll
      for (int ct = 0; ct < 4; ++ct) {
        float ce = colp[ct];
        ce += __shfl_xor(ce, 16, 64);
        ce += __shfl_xor(ce, 32, 64);
        if (qd == 0) redcol[wx * 64 + ct * 16 + l15][wy] = ce;
      }
    }
    __syncthreads();
    if (t < 128) {
      atomicAdd(&rowexp[ti + t], redrow[t][0] + redrow[t][1]);
      if (offdiag) atomicAdd(&rowexp[tj + t], redcol[t][0] + redcol[t][1]);
    }
  }

  // ---- done-counter; last block finalizes in-kernel ----
  __threadfence();
  if (t == 0) {
    const int old = __hip_atomic_fetch_add(done, 1, __ATOMIC_ACQ_REL,
                                           __HIP_MEMORY_SCOPE_AGENT);
    lastf = (old == 1055) ? 1 : 0;
  }
  __syncthreads();
  if (lastf) {
    float c = 0.f, q = 0.f;
    for (int m = t; m < 4096; m += 256) {
      const float re = __hip_atomic_load(&rowexp[m], __ATOMIC_RELAXED,
                                         __HIP_MEMORY_SCOPE_AGENT);
      const float ps = __hip_atomic_load(&possum[m], __ATOMIC_RELAXED,
                                         __HIP_MEMORY_SCOPE_AGENT);
      const float cn = __hip_atomic_load(&cntw[m], __ATOMIC_RELAXED,
                                         __HIP_MEMORY_SCOPE_AGENT);
      c += logf(re) - ps / fmaxf(cn, 1.0f);
      q += qpart[m];
    }
#pragma unroll
    for (int off = 1; off < 64; off <<= 1) {
      c += __shfl_xor(c, off, 64);
      q += __shfl_xor(q, off, 64);
    }
    if (lane == 0) { fc[wave] = c; fq[wave] = q; }
    __syncthreads();
    if (t == 0) {
      const float C = fc[0] + fc[1] + fc[2] + fc[3];
      const float Q = fq[0] + fq[1] + fq[2] + fq[3];
      const float D = __hip_atomic_load(dtot, __ATOMIC_RELAXED,
                                        __HIP_MEMORY_SCOPE_AGENT);
      // num_pos = B (diagonal positives guaranteed)
      out[0] = C * (1.0f / 4096.0f) + 0.5f * (D * (1.0f / 16777216.0f)) +
               0.01f * (Q * (1.0f / 524288.0f));
    }
  }
}

extern "C" void kernel_launch(void* const* d_in, const int* in_sizes, int n_in,
                              void* d_out, int out_size, void* d_ws, size_t ws_size,
                              hipStream_t stream) {
  const float* logits = (const float*)d_in[0];
  const float* hash = (const float*)d_in[1];
  const float* teacher = (const float*)d_in[2];
  const void* mask = d_in[3];
  float* out = (float*)d_out;

  char* ws = (char*)d_ws;
  float* rowexp = (float*)(ws + 0);
  float* possum = (float*)(ws + 16384);
  float* cntw = (float*)(ws + 32768);
  float* qpart = (float*)(ws + 49152);
  float* dtot = (float*)(ws + 65536);
  int* done = (int*)(ws + 65544);
  unsigned short* P = (unsigned short*)(ws + 98304);  // 4096x1024 bf16 = 8 MB

  prep<<<1024, 256, 0, stream>>>(logits, hash, teacher, P, qpart, rowexp,
                                 possum, cntw, dtot, done);
  mega<<<1056, 256, 0, stream>>>(P, mask, rowexp, possum, cntw, dtot, done,
                                 qpart, out);
}

// Round 5
// 173.703 us; speedup vs baseline: 1.5606x; 1.5606x over previous
//
#include <hip/hip_runtime.h>

// HashLoss: contrastive (logsumexp over ln@ln^T/0.2) + 0.5*MSE(H@H^T/128, Tn@Tn^T)
//         + 0.01*mean||logits|-1|
// B=4096. P[4096][1024] bf16 = [ln | hash/sqrt128 | tn]. Role-split mega kernel:
//  - blocks 0..527:    D-role: 128x128 triangle tiles of Hs@Hs^T - T@T^T (K=896)
//  - blocks 528..1055: S-role: 128x128 triangle tiles of ln@ln^T (K=128) + mask epilogue
// NO device-scope fences/acquire atomics inside mega (R4's acq_rel+threadfence per
// block invalidated L2 1056x -> FETCH 6->60MB, 2x slowdown). Relaxed atomics only;
// separate finalize dispatch provides ordering.

typedef unsigned short u16x8 __attribute__((ext_vector_type(8)));
typedef __bf16 bf16x8 __attribute__((ext_vector_type(8)));
typedef float f32x4 __attribute__((ext_vector_type(4)));

__device__ __forceinline__ unsigned short f2bf(float f) {
  union { float f; unsigned int u; } v; v.f = f;
  unsigned int u = v.u;
  return (unsigned short)((u + 0x7FFFu + ((u >> 16) & 1u)) >> 16);  // RNE
}

// ---- prep: one wave per row. 1024 blocks x 256 threads.
__global__ __launch_bounds__(256) void prep(const float* __restrict__ logits,
                                            const float* __restrict__ hash,
                                            const float* __restrict__ teacher,
                                            unsigned short* __restrict__ P,
                                            float* __restrict__ qpart,
                                            float* __restrict__ rowexp,
                                            float* __restrict__ possum,
                                            float* __restrict__ cntw,
                                            float* __restrict__ dtot) {
  const int r = blockIdx.x * 4 + (threadIdx.x >> 6);
  const int lane = threadIdx.x & 63;
  float tv[12];
  float ss = 0.f;
#pragma unroll
  for (int i = 0; i < 12; ++i) {
    tv[i] = teacher[(size_t)r * 768 + i * 64 + lane];
    ss += tv[i] * tv[i];
  }
  const float l0 = logits[(size_t)r * 128 + lane];
  const float l1 = logits[(size_t)r * 128 + 64 + lane];
  const float h0 = hash[(size_t)r * 128 + lane];
  const float h1 = hash[(size_t)r * 128 + 64 + lane];
  float ssl = l0 * l0 + l1 * l1;
  float qv = fabsf(fabsf(l0) - 1.f) + fabsf(fabsf(l1) - 1.f);
#pragma unroll
  for (int off = 1; off < 64; off <<= 1) {
    ss += __shfl_xor(ss, off, 64);
    ssl += __shfl_xor(ssl, off, 64);
    qv += __shfl_xor(qv, off, 64);
  }
  const float rnt = 1.f / fmaxf(sqrtf(ss), 1e-12f);
  const float rnl = 1.f / fmaxf(sqrtf(ssl), 1e-12f);
  unsigned short* Pr = P + (size_t)r * 1024;
  Pr[lane] = f2bf(l0 * rnl);
  Pr[64 + lane] = f2bf(l1 * rnl);
  // (H/sqrt128)@(H/sqrt128)^T == H@H^T/128
  Pr[128 + lane] = f2bf(h0 * 0.08838834764831845f);
  Pr[192 + lane] = f2bf(h1 * 0.08838834764831845f);
#pragma unroll
  for (int i = 0; i < 12; ++i) Pr[256 + i * 64 + lane] = f2bf(tv[i] * rnt);
  if (lane == 0) {
    qpart[r] = qv;
    rowexp[r] = 0.f; possum[r] = 0.f; cntw[r] = 0.f;
    if (r == 0) *dtot = 0.f;
  }
}

// Stage 128 rows x 64 cols of P (A: rows ti+, and if offdiag B: rows tj+) via
// global_load_lds(16B). LDS[row][slot] = global[row][slot ^ (row&7)], pitch 64.
#define STAGE64(COL0)                                                          \
  {                                                                            \
    _Pragma("unroll") for (int it = 0; it < 4; ++it) {                         \
      const int task = it * 256 + t;                                           \
      const int row = task >> 3;                                               \
      const int g = (task & 7) ^ (row & 7);                                    \
      const unsigned short* gpA =                                              \
          P + (size_t)(ti + row) * 1024 + (COL0) + g * 8;                      \
      __builtin_amdgcn_global_load_lds(                                        \
          (const __attribute__((address_space(1))) void*)gpA,                  \
          (__attribute__((address_space(3))) void*)&S[it * 2048 + wave * 512], \
          16, 0, 0);                                                           \
      if (offdiag) {                                                           \
        const unsigned short* gpB =                                            \
            P + (size_t)(tj + row) * 1024 + (COL0) + g * 8;                    \
        __builtin_amdgcn_global_load_lds(                                      \
            (const __attribute__((address_space(1))) void*)gpB,                \
            (__attribute__((address_space(3)))                                 \
                 void*)&S[8192 + it * 2048 + wave * 512],                      \
            16, 0, 0);                                                         \
      }                                                                        \
    }                                                                          \
  }

// 2 k-steps x 16 MFMA on the staged 64-col chunk. Wave (wy,wx) owns the
// 64x64 quadrant at rows wy*64, cols wx*64 as 4x4 tiles of 16x16.
#define MFMA_CHUNK()                                                           \
  {                                                                            \
    _Pragma("unroll") for (int ks = 0; ks < 2; ++ks) {                         \
      bf16x8 af[4], bfr[4];                                                    \
      _Pragma("unroll") for (int rt = 0; rt < 4; ++rt) {                       \
        const int ar = wy * 64 + rt * 16 + l15;                                \
        af[rt] =                                                               \
            *(const bf16x8*)&S[ar * 64 + ((ks * 4 + qd) ^ (l15 & 7)) * 8];     \
      }                                                                        \
      _Pragma("unroll") for (int ct = 0; ct < 4; ++ct) {                       \
        const int br = wx * 64 + ct * 16 + l15;                                \
        bfr[ct] = *(const bf16x8*)&S[boff + br * 64 +                          \
                                     ((ks * 4 + qd) ^ (l15 & 7)) * 8];         \
      }                                                                        \
      _Pragma("unroll") for (int rt = 0; rt < 4; ++rt)                         \
          _Pragma("unroll") for (int ct = 0; ct < 4; ++ct) acc[rt][ct] =       \
          __builtin_amdgcn_mfma_f32_16x16x32_bf16(af[rt], bfr[ct],             \
                                                  acc[rt][ct], 0, 0, 0);       \
    }                                                                          \
  }

__global__ __launch_bounds__(256, 3) void mega(const unsigned short* __restrict__ P,
                                               const void* __restrict__ mask,
                                               float* __restrict__ rowexp,
                                               float* __restrict__ possum,
                                               float* __restrict__ cntw,
                                               float* __restrict__ dtot) {
  __shared__ __align__(16) unsigned short S[16384];  // A @0, B @8192 (shorts)
  __shared__ float redrow[128][2], redcol[128][2], red4[4];

  const int t = threadIdx.x;
  const int wave = t >> 6, lane = t & 63;
  const int qd = lane >> 4, l15 = lane & 15;
  const int wy = wave >> 1, wx = wave & 1;

  const int b = (int)blockIdx.x;
  const bool isD = (b & 1) == 0;          // interleave roles for CU balance
  const int bb = b >> 1;
  // XCD swizzle (528 = 8*66), then triangle decode over 32 block-rows.
  const int l = (bb & 7) * 66 + (bb >> 3);
  int bi = (int)((65.0f - sqrtf(4225.0f - 8.0f * (float)l)) * 0.5f);
  while (bi * (65 - bi) / 2 > l) --bi;
  while ((bi + 1) * (64 - bi) / 2 <= l) ++bi;
  const int bj = bi + (l - bi * (65 - bi) / 2);
  const int ti = bi * 128, tj = bj * 128;
  const bool offdiag = (bi != bj);
  const int boff = offdiag ? 8192 : 0;

  f32x4 acc[4][4];
#pragma unroll
  for (int rt = 0; rt < 4; ++rt)
#pragma unroll
    for (int ct = 0; ct < 4; ++ct) acc[rt][ct] = {0.f, 0.f, 0.f, 0.f};

  if (isD) {
    // D = Hs@Hs^T - T@T^T : chunks 0..11 = T (cols 256..1023), then negate,
    // chunks 12..13 = Hs (cols 128..255).
    for (int kc = 0; kc < 14; ++kc) {
      const int col0 = (kc < 12) ? (256 + kc * 64) : (128 + (kc - 12) * 64);
      __syncthreads();
      STAGE64(col0);
      __syncthreads();
      if (kc == 12) {
#pragma unroll
        for (int rt = 0; rt < 4; ++rt)
#pragma unroll
          for (int ct = 0; ct < 4; ++ct) acc[rt][ct] = -acc[rt][ct];
      }
      MFMA_CHUNK();
    }
    float dsum = 0.f;
#pragma unroll
    for (int rt = 0; rt < 4; ++rt)
#pragma unroll
      for (int ct = 0; ct < 4; ++ct)
#pragma unroll
        for (int i = 0; i < 4; ++i) dsum += acc[rt][ct][i] * acc[rt][ct][i];
#pragma unroll
    for (int off = 1; off < 64; off <<= 1) dsum += __shfl_xor(dsum, off, 64);
    if (lane == 0) red4[wave] = dsum;
    __syncthreads();
    if (t == 0)
      atomicAdd(dtot, (offdiag ? 2.0f : 1.0f) *
                          (red4[0] + red4[1] + red4[2] + red4[3]));
  } else {
    // S-role: ln gram, K=128 (cols 0..127).
    for (int kc = 0; kc < 2; ++kc) {
      const int col0 = kc * 64;
      __syncthreads();
      STAGE64(col0);
      __syncthreads();
      MFMA_CHUNK();
    }

    // ---- mask tiles -> LDS (coalesced), reusing S ----
    __syncthreads();
    unsigned char* MD = (unsigned char*)S;          // [mrow][ncol], 16KB
    unsigned char* MM = (unsigned char*)S + 16384;  // [ncol][mrow], 16KB
    const bool is_byte = ((const unsigned char*)mask)[4097] != 0;
    if (is_byte) {
      const unsigned char* m8 = (const unsigned char*)mask;
#pragma unroll
      for (int it = 0; it < 4; ++it) {
        const int task = it * 256 + t;
        const int row = task >> 3, seg = task & 7;
        *(uint4*)&MD[row * 128 + seg * 16] =
            *(const uint4*)&m8[(size_t)(ti + row) * 4096 + tj + seg * 16];
        if (offdiag)
          *(uint4*)&MM[row * 128 + seg * 16] =
              *(const uint4*)&m8[(size_t)(tj + row) * 4096 + ti + seg * 16];
      }
    } else {
      const unsigned int* m32 = (const unsigned int*)mask;
#pragma unroll
      for (int it = 0; it < 16; ++it) {
        const int task = it * 256 + t;
        const int row = task >> 5, seg = task & 31;
        uint4 v = *(const uint4*)&m32[(size_t)(ti + row) * 4096 + tj + seg * 4];
        uchar4 pk;
        pk.x = v.x ? 1 : 0; pk.y = v.y ? 1 : 0;
        pk.z = v.z ? 1 : 0; pk.w = v.w ? 1 : 0;
        *(uchar4*)&MD[row * 128 + seg * 4] = pk;
        if (offdiag) {
          uint4 w = *(const uint4*)&m32[(size_t)(tj + row) * 4096 + ti + seg * 4];
          uchar4 pm;
          pm.x = w.x ? 1 : 0; pm.y = w.y ? 1 : 0;
          pm.z = w.z ? 1 : 0; pm.w = w.w ? 1 : 0;
          *(uchar4*)&MM[row * 128 + seg * 4] = pm;
        }
      }
    }
    __syncthreads();

    float colp[4] = {0.f, 0.f, 0.f, 0.f};
#pragma unroll
    for (int rt = 0; rt < 4; ++rt) {
#pragma unroll
      for (int r = 0; r < 4; ++r) {
        const int mrow = wy * 64 + rt * 16 + qd * 4 + r;  // C/D: row=qd*4+reg
        const int m = ti + mrow;
        float se = 0.f;
#pragma unroll
        for (int ct = 0; ct < 4; ++ct) {
          const int ncol = wx * 64 + ct * 16 + l15;       // C/D: col=lane&15
          const int n = tj + ncol;
          const float sim = acc[rt][ct][r] * 5.0f;        // /TEMPERATURE
          const float e = __expf(sim);
          if (offdiag || mrow != ncol) se += e;           // diag excluded
          if (offdiag) colp[ct] += e;
          if (MD[mrow * 128 + ncol]) {                    // sparse positives
            atomicAdd(&possum[m], sim);
            atomicAdd(&cntw[m], 1.0f);
          }
          if (offdiag && MM[ncol * 128 + mrow]) {         // mirror (n, m)
            atomicAdd(&possum[n], sim);
            atomicAdd(&cntw[n], 1.0f);
          }
        }
#pragma unroll
        for (int off = 1; off < 16; off <<= 1) se += __shfl_xor(se, off, 64);
        if (l15 == 0) redrow[mrow][wx] = se;
      }
    }
    if (offdiag) {
#pragma unroll
      for (int ct = 0; ct < 4; ++ct) {
        float ce = colp[ct];
        ce += __shfl_xor(ce, 16, 64);
        ce += __shfl_xor(ce, 32, 64);
        if (qd == 0) redcol[wx * 64 + ct * 16 + l15][wy] = ce;
      }
    }
    __syncthreads();
    if (t < 128) {
      atomicAdd(&rowexp[ti + t], redrow[t][0] + redrow[t][1]);
      if (offdiag) atomicAdd(&rowexp[tj + t], redcol[t][0] + redcol[t][1]);
    }
  }
}

__global__ __launch_bounds__(1024) void finalize(const float* __restrict__ rowexp,
                                                 const float* __restrict__ possum,
                                                 const float* __restrict__ cnt,
                                                 const float* __restrict__ qpart,
                                                 const float* __restrict__ dtot,
                                                 float* __restrict__ out) {
  const int t = threadIdx.x;
  const int wave = t >> 6, lane = t & 63;
  float c = 0.f, q = 0.f;
  for (int m = t; m < 4096; m += 1024) {
    c += logf(rowexp[m]) - possum[m] / fmaxf(cnt[m], 1.0f);
    q += qpart[m];
  }
#pragma unroll
  for (int off = 1; off < 64; off <<= 1) {
    c += __shfl_xor(c, off, 64);
    q += __shfl_xor(q, off, 64);
  }
  __shared__ float sc[16], sq[16];
  if (lane == 0) { sc[wave] = c; sq[wave] = q; }
  __syncthreads();
  if (t == 0) {
    float C = 0.f, Q = 0.f;
    for (int i = 0; i < 16; ++i) { C += sc[i]; Q += sq[i]; }
    // every row has its diagonal positive -> num_pos = B = 4096
    out[0] = C * (1.0f / 4096.0f) + 0.5f * (dtot[0] * (1.0f / 16777216.0f)) +
             0.01f * (Q * (1.0f / 524288.0f));
  }
}

extern "C" void kernel_launch(void* const* d_in, const int* in_sizes, int n_in,
                              void* d_out, int out_size, void* d_ws, size_t ws_size,
                              hipStream_t stream) {
  const float* logits = (const float*)d_in[0];
  const float* hash = (const float*)d_in[1];
  const float* teacher = (const float*)d_in[2];
  const void* mask = d_in[3];
  float* out = (float*)d_out;

  char* ws = (char*)d_ws;
  float* rowexp = (float*)(ws + 0);
  float* possum = (float*)(ws + 16384);
  float* cntw = (float*)(ws + 32768);
  float* qpart = (float*)(ws + 49152);
  float* dtot = (float*)(ws + 65536);
  unsigned short* P = (unsigned short*)(ws + 98304);  // 4096x1024 bf16 = 8 MB

  prep<<<1024, 256, 0, stream>>>(logits, hash, teacher, P, qpart, rowexp,
                                 possum, cntw, dtot);
  mega<<<1056, 256, 0, stream>>>(P, mask, rowexp, possum, cntw, dtot);
  finalize<<<1, 1024, 0, stream>>>(rowexp, possum, cntw, qpart, dtot, out);
}